// Round 6
// baseline (316.358 us; speedup 1.0000x reference)
//
#include <hip/hip_runtime.h>

typedef __bf16 bfv8 __attribute__((ext_vector_type(8)));
typedef float f32x4 __attribute__((ext_vector_type(4)));
typedef float f32x2 __attribute__((ext_vector_type(2)));
typedef short shortv8 __attribute__((ext_vector_type(8)));
typedef unsigned short usv8 __attribute__((ext_vector_type(8)));

__device__ __forceinline__ float b2f(unsigned short u) {
  unsigned int v = ((unsigned int)u) << 16;
  float f;
  __builtin_memcpy(&f, &v, 4);
  return f;
}
__device__ __forceinline__ unsigned short f2b(float f) {
  unsigned int u;
  __builtin_memcpy(&u, &f, 4);
  u += 0x7fffu + ((u >> 16) & 1u);
  return (unsigned short)(u >> 16);
}

// unpack a dword holding two bf16 (lo = even channel, hi = odd channel) to float2
__device__ __forceinline__ f32x2 bf2x(unsigned int u) {
  f32x2 r;
  r.x = __builtin_bit_cast(float, u << 16);
  r.y = __builtin_bit_cast(float, u & 0xffff0000u);
  return r;
}

// DPP neighbor fetch (compile-time control); all lanes active at every call site.
// 0xB1 = quad_perm xor1, 0x4E = quad_perm xor2, 0x124 = row_ror:4, 0x128 = row_ror:8
template <int CTRL>
__device__ __forceinline__ float dpp_mv(float x) {
  int xi = __builtin_bit_cast(int, x);
  int yi = __builtin_amdgcn_update_dpp(0, xi, CTRL, 0xf, 0xf, true);
  return __builtin_bit_cast(float, yi);
}

__device__ __forceinline__ float tanh_fast(float x) {
  // tanh(x) = 1 - 2/(e^{2x}+1); rcp is ~1ulp, output is bf16 -> negligible
  float e2 = __expf(2.f * x);
  float r = __builtin_amdgcn_rcpf(e2 + 1.f);
  float th = fmaf(-2.f, r, 1.f);
  if (!(th == th)) th = 0.f;
  return th;
}

// ---------------- dtype probe (x): f32-as-bf16 shows ~48% absurd exponents ----
__global__ void probe_kernel(const unsigned short* __restrict__ x, int* __restrict__ flag) {
  int lane = threadIdx.x;  // 64 threads
  int cnt = 0;
  for (int i = lane; i < 4096; i += 64) {
    unsigned int e = (x[i] >> 7) & 0xffu;
    if (e >= 0x86u) cnt++;  // |val| >= 128
  }
#pragma unroll
  for (int off = 1; off < 64; off <<= 1) cnt += __shfl_xor(cnt, off, 64);
  if (lane == 0) *flag = (cnt > 100) ? 1 : 0;
}

// ---------------- fused: conv_x | count | conv_params (all 256-thread) ----------------
// conv_x only does work when flag==1 (f32 input); bf16 inputs are read in place
// by gemm1, so the copy is skipped entirely.
// Wl1@0 bl1@65536 Wr1@65792 br1@131328 att1@131584 bias1@131840
// Wl2@132096 bl2@136192 Wr2@136208 br2@140304 att2@140320 bias2@140336  total 140352
#define P_TOT 140352
__global__ __launch_bounds__(256) void fused_pre_kernel(
    const void* __restrict__ x, unsigned short* __restrict__ Xc,
    const int* __restrict__ flagp, int NX,
    const int* __restrict__ ei, int E, int Nn, int* __restrict__ cnt,
    const void* p0, const void* p1, const void* p2, const void* p3,
    const void* p4, const void* p5, const void* p6, const void* p7,
    const void* p8, const void* p9, const void* p10, const void* p11,
    unsigned short* __restrict__ Pc, int nb_convx, int nb_count) {
  int b = blockIdx.x;
  int t = threadIdx.x;
  if (b < nb_convx) {
    // ---- conv_x (f32 -> bf16 only; bf16 passthrough handled in gemm1) ----
    if (!*flagp) return;
    int i = (b * 256 + t) * 4;
    if (i >= NX) return;
    float4 f = *reinterpret_cast<const float4*>((const float*)x + i);
    ushort4 o;
    o.x = f2b(f.x); o.y = f2b(f.y); o.z = f2b(f.z); o.w = f2b(f.w);
    *reinterpret_cast<ushort4*>(Xc + i) = o;
  } else if (b < nb_convx + nb_count) {
    // ---- count (degree histogram incl. self-loops) ----
    int i = (b - nb_convx) * 256 + t;
    int total = E + Nn;
    if (i >= total) return;
    int d = (i < E) ? ei[E + i] : (i - E);
    if ((unsigned)d >= (unsigned)Nn) d = 0;
    atomicAdd(&cnt[d], 1);
  } else {
    // ---- conv_params ----
    int i = (b - nb_convx - nb_count) * 256 + t;
    if (i >= P_TOT) return;
    const int offs[13] = {0, 65536, 65792, 131328, 131584, 131840, 132096,
                          136192, 136208, 140304, 140320, 140336, P_TOT};
    const void* ptrs[12] = {p0, p1, p2, p3, p4, p5, p6, p7, p8, p9, p10, p11};
    int flag = *flagp;
    int k = 0;
    while (i >= offs[k + 1]) k++;
    int local = i - offs[k];
    unsigned short v;
    if (flag) v = f2b(((const float*)ptrs[k])[local]);
    else v = ((const unsigned short*)ptrs[k])[local];
    Pc[i] = v;
  }
}

// ---------------- fused: scan1 (+cursor zero) | merged W transposes (1024-thread) ----
__global__ __launch_bounds__(1024) void fused_mid_kernel(
    const int* __restrict__ cnt, int* __restrict__ row_start, int* __restrict__ blkTot,
    int* __restrict__ cursor, int Nn, int nb_scan,
    const unsigned short* __restrict__ Pc,
    unsigned short* __restrict__ WT1, unsigned short* __restrict__ WT2) {
  int b = blockIdx.x;
  int t = threadIdx.x;
  if (b < nb_scan) {
    // ---- scan1: block-local exclusive prefix over degree counts ----
    __shared__ int buf[1024];
    int i = b * 1024 + t;
    int v = (i < Nn) ? cnt[i] : 0;
    buf[t] = v;
    if (i < Nn) cursor[i] = 0;  // fold cursor memset in here (fill runs later)
    __syncthreads();
    for (int off = 1; off < 1024; off <<= 1) {
      int x = (t >= off) ? buf[t - off] : 0;
      __syncthreads();
      buf[t] += x;
      __syncthreads();
    }
    if (i < Nn) row_start[i] = buf[t] - v;  // block-local exclusive
    if (t == 1023) blkTot[b] = buf[1023];
  } else {
    // ---- transpose: WT1[n][k]=W1[k][n], WT2[n][k]=W2[k][n] ----
    int idx = (b - nb_scan) * 1024 + t;
    if (idx < 512 * 256) {
      int n = idx >> 8, k = idx & 255;
      WT1[idx] = (n < 256) ? Pc[0 + k * 256 + n]               // Wl1
                           : Pc[65792 + k * 256 + (n - 256)];  // Wr1
    } else {
      int j = idx - 512 * 256;
      if (j < 32 * 256) {
        int n = j >> 8, k = j & 255;
        WT2[j] = (n < 16) ? Pc[132096 + k * 16 + n]            // Wl2
                          : Pc[136208 + k * 16 + (n - 16)];    // Wr2
      }
    }
  }
}

// ---------------- scan2: prefix over block totals; blkOff[0..64] all defined ----
__global__ __launch_bounds__(64) void scan2_kernel(const int* __restrict__ blkTot,
                                                   int* __restrict__ blkOff, int nb,
                                                   int* __restrict__ row_start, int Nn,
                                                   int total) {
  int lane = threadIdx.x;  // nb <= 64
  int v = (lane < nb) ? blkTot[lane] : 0;
  int s = v;
#pragma unroll
  for (int off = 1; off < 64; off <<= 1) {
    int u = __shfl_up(s, off, 64);
    if (lane >= off) s += u;
  }
  int excl = s - v;
  blkOff[lane] = excl;            // lanes >= nb hold the full total (v=0 there)
  if (lane == 63) blkOff[64] = s; // virtual block 64 (Nn == 64*1024 case)
  int idx = Nn >> 10;             // block index of element Nn (<= 64)
  int bo = (idx >= 64) ? __shfl(s, 63, 64) : __shfl(excl, idx, 64);
  if (lane == 0) row_start[Nn] = total - bo;  // so row_start[Nn]+blkOff[idx]==total
}

// ---------------- fill: scatter src ids to CSR (block-local row_start + blkOff) ----
__global__ __launch_bounds__(256) void fill_kernel(const int* __restrict__ ei, int E, int Nn,
                                                   const int* __restrict__ row_start,
                                                   const int* __restrict__ blkOff,
                                                   int* __restrict__ cursor,
                                                   int* __restrict__ csr_src) {
  int i = blockIdx.x * 256 + threadIdx.x;
  int total = E + Nn;
  if (i >= total) return;
  int s, d;
  if (i < E) { s = ei[i]; d = ei[E + i]; } else { s = i - E; d = i - E; }
  if ((unsigned)d >= (unsigned)Nn) d = 0;
  if ((unsigned)s >= (unsigned)Nn) s = 0;
  int pos = row_start[d] + blkOff[d >> 10] + atomicAdd(&cursor[d], 1);
  if ((unsigned)pos < (unsigned)total) csr_src[pos] = s;
}

// ---------------- GEMM1: C[M,512] = X[M,256] @ [Wl1|Wr1] + bias (bf16 out)
// r5 lesson: sibling blocks on different XCDs double-fetch X through disjoint
// L2s. Fix structurally: ONE block owns a 64-row slab and computes ALL 512
// output cols -> X fetched exactly once, no cross-block locality assumption.
// X staged coalesced in 16KB dbuf LDS; WT direct from L2 (b-load pattern = 16
// rows x contiguous 64B line -> L2-friendly). acc[4][8] = 128 VGPR/warp.
__global__ __launch_bounds__(256) void gemm1_kernel(
    const unsigned short* __restrict__ Xc,     // bf16 [M,256] (converted)
    const unsigned short* __restrict__ x_raw,  // raw input (bf16 case)
    const int* __restrict__ flagp,
    const unsigned short* __restrict__ WT,     // bf16 [512,256]
    const unsigned short* __restrict__ bl, const unsigned short* __restrict__ br,
    unsigned short* __restrict__ C, int M) {
  __shared__ unsigned short smem[8704];  // staging 2x4096; epilogue 4x2176 (reuse)
  const unsigned short* X = (*flagp) ? Xc : x_raw;
  const int t = threadIdx.x;
  const int lane = t & 63;
  const int w = t >> 6;
  const int quad = lane >> 4;
  const int l16 = lane & 15;
  const int m_blk = blockIdx.x * 64;
  const int n_base = w * 128;  // warp owns 128 output cols

  const int st_row = t >> 2;  // 0..63
  const int st_seg = t & 3;   // covers segs st_seg and st_seg+4

  f32x4 acc[4][8];
#pragma unroll
  for (int i = 0; i < 4; i++)
#pragma unroll
    for (int j = 0; j < 8; j++) acc[i][j] = (f32x4){0.f, 0.f, 0.f, 0.f};

  int gr = m_blk + st_row;
  if (gr >= M) gr = M - 1;
  const unsigned short* xrow = X + (size_t)gr * 256;

  shortv8 st0 = *reinterpret_cast<const shortv8*>(xrow + st_seg * 8);
  shortv8 st1 = *reinterpret_cast<const shortv8*>(xrow + st_seg * 8 + 32);
  *reinterpret_cast<shortv8*>(smem + st_row * 64 + ((st_seg ^ (st_row & 7)) * 8)) = st0;
  *reinterpret_cast<shortv8*>(smem + st_row * 64 + (((st_seg + 4) ^ (st_row & 7)) * 8)) = st1;
  __syncthreads();

#pragma unroll
  for (int c = 0; c < 4; c++) {
    if (c < 3) {
      st0 = *reinterpret_cast<const shortv8*>(xrow + (c + 1) * 64 + st_seg * 8);
      st1 = *reinterpret_cast<const shortv8*>(xrow + (c + 1) * 64 + st_seg * 8 + 32);
    }
    const unsigned short* bb = smem + (c & 1) * 4096;
#pragma unroll
    for (int sub = 0; sub < 2; sub++) {
      int seg_r = sub * 4 + quad;
      bfv8 a[4], b[8];
#pragma unroll
      for (int i = 0; i < 4; i++) {
        int lrow = 16 * i + l16;  // 0..63 within tile
        a[i] = *reinterpret_cast<const bfv8*>(bb + lrow * 64 + ((seg_r ^ (lrow & 7)) * 8));
      }
#pragma unroll
      for (int j = 0; j < 8; j++) {
        int col = n_base + 16 * j + l16;
        b[j] = *reinterpret_cast<const bfv8*>(WT + (size_t)col * 256 + c * 64 + sub * 32 +
                                              quad * 8);
      }
#pragma unroll
      for (int i = 0; i < 4; i++)
#pragma unroll
        for (int j = 0; j < 8; j++)
          acc[i][j] = __builtin_amdgcn_mfma_f32_16x16x32_bf16(a[i], b[j], acc[i][j], 0, 0, 0);
    }
    if (c < 3) {
      int buf = (c + 1) & 1;
      *reinterpret_cast<shortv8*>(smem + buf * 4096 + st_row * 64 +
                                  ((st_seg ^ (st_row & 7)) * 8)) = st0;
      *reinterpret_cast<shortv8*>(smem + buf * 4096 + st_row * 64 +
                                  (((st_seg + 4) ^ (st_row & 7)) * 8)) = st1;
      __syncthreads();
    }
  }

  __syncthreads();  // staging buffers dead; epilogue regions may overlap them
  // epilogue: per-warp-private 16-row x 128-col slices (136-short padded rows);
  // same-wave LDS ops are in-order, so no barriers inside the i-loop.
  unsigned short* lt = smem + w * 2176;
#pragma unroll
  for (int i = 0; i < 4; i++) {
#pragma unroll
    for (int j = 0; j < 8; j++) {
      int col = n_base + 16 * j + l16;
      float bias = (col < 256) ? b2f(bl[col]) : b2f(br[col - 256]);
#pragma unroll
      for (int r = 0; r < 4; r++)
        lt[(quad * 4 + r) * 136 + 16 * j + l16] = f2b(acc[i][j][r] + bias);
    }
#pragma unroll
    for (int pass = 0; pass < 4; pass++) {
      int row = pass * 4 + (lane >> 4);
      int colg = (lane & 15) * 8;
      shortv8 v = *reinterpret_cast<const shortv8*>(lt + row * 136 + colg);
      int grow = m_blk + 16 * i + row;
      if (grow < M)
        *reinterpret_cast<shortv8*>(C + (size_t)grow * 512 + n_base + colg) = v;
    }
  }
}

// ---------------- GEMM2: C2[M,32] = H[M,256] @ [Wl2|Wr2] + bias (f32 out)
// 64-row tiles, H staged coalesced in 16KB dbuf LDS, WT2 (16KB, L2-hot) direct.
__global__ __launch_bounds__(256) void gemm2_kernel(
    const unsigned short* __restrict__ H, const unsigned short* __restrict__ WT,
    const unsigned short* __restrict__ bl, const unsigned short* __restrict__ br,
    float* __restrict__ C, int M) {
  __shared__ unsigned short smem[8192];  // 2 x (64 rows x 64 k), XOR seg-swizzle
  const int t = threadIdx.x;
  const int lane = t & 63;
  const int w = t >> 6;
  const int quad = lane >> 4;
  const int l16 = lane & 15;
  const int m_blk = blockIdx.x * 64;
  const int wrow = w * 16;  // warp's 16-row slice

  const int st_row = t >> 2;  // 0..63
  const int st_seg = t & 3;   // covers segs st_seg and st_seg+4

  f32x4 acc[2];
  acc[0] = (f32x4){0.f, 0.f, 0.f, 0.f};
  acc[1] = (f32x4){0.f, 0.f, 0.f, 0.f};

  int gr = m_blk + st_row;
  if (gr >= M) gr = M - 1;
  const unsigned short* hrow = H + (size_t)gr * 256;

  shortv8 st0 = *reinterpret_cast<const shortv8*>(hrow + st_seg * 8);
  shortv8 st1 = *reinterpret_cast<const shortv8*>(hrow + st_seg * 8 + 32);
  *reinterpret_cast<shortv8*>(smem + st_row * 64 + ((st_seg ^ (st_row & 7)) * 8)) = st0;
  *reinterpret_cast<shortv8*>(smem + st_row * 64 + (((st_seg + 4) ^ (st_row & 7)) * 8)) = st1;
  __syncthreads();

#pragma unroll
  for (int c = 0; c < 4; c++) {
    if (c < 3) {
      st0 = *reinterpret_cast<const shortv8*>(hrow + (c + 1) * 64 + st_seg * 8);
      st1 = *reinterpret_cast<const shortv8*>(hrow + (c + 1) * 64 + st_seg * 8 + 32);
    }
    const unsigned short* bb = smem + (c & 1) * 4096;
#pragma unroll
    for (int sub = 0; sub < 2; sub++) {
      int seg_r = sub * 4 + quad;
      int lrow = wrow + l16;
      bfv8 a = *reinterpret_cast<const bfv8*>(bb + lrow * 64 + ((seg_r ^ (lrow & 7)) * 8));
      bfv8 b[2];
#pragma unroll
      for (int j = 0; j < 2; j++) {
        int col = 16 * j + l16;
        b[j] = *reinterpret_cast<const bfv8*>(WT + (size_t)col * 256 + c * 64 + sub * 32 +
                                              quad * 8);
      }
#pragma unroll
      for (int j = 0; j < 2; j++)
        acc[j] = __builtin_amdgcn_mfma_f32_16x16x32_bf16(a, b[j], acc[j], 0, 0, 0);
    }
    if (c < 3) {
      int buf = (c + 1) & 1;
      *reinterpret_cast<shortv8*>(smem + buf * 4096 + st_row * 64 +
                                  ((st_seg ^ (st_row & 7)) * 8)) = st0;
      *reinterpret_cast<shortv8*>(smem + buf * 4096 + st_row * 64 +
                                  (((st_seg + 4) ^ (st_row & 7)) * 8)) = st1;
      __syncthreads();
    }
  }

#pragma unroll
  for (int j = 0; j < 2; j++) {
    int col = 16 * j + l16;
    float bias = (j == 0) ? b2f(bl[l16]) : b2f(br[l16]);
#pragma unroll
    for (int r = 0; r < 4; r++) {
      int row = m_blk + wrow + quad * 4 + r;
      if (row < M) C[(size_t)row * 32 + col] = acc[j][r] + bias;
    }
  }
}

// ---------------- layer-1 aggregation: 4 edges/wave-iteration + tanh ----------------
// Edge slot g = lane>>4 (4 edges/iter); each lane owns 16 channels
// (c0 = (lane&15)*16) as 8x f32x2 (V_PK packed f32), gathered as 2x uint4.
// Head = quad within the 16-lane group (lanes 4q..4q+3 cover ch [64q,64q+64)):
// score reduce = DPP xor1/xor2 only. Degree~9 -> 2.6 iters/node (was 4.7).
// csr_src indices hoisted per 64-edge chunk; unroll 2 keeps 4 gathers in flight.
__global__ __launch_bounds__(256) void agg1_kernel(
    const unsigned short* __restrict__ C1,    // [N,512]: 0-255 xl, 256-511 xr
    const unsigned short* __restrict__ att1,  // [256]
    const unsigned short* __restrict__ bias1, // [256]
    const int* __restrict__ row_start, const int* __restrict__ blkOff,
    const int* __restrict__ csr_src,
    unsigned short* __restrict__ H1,          // [N,256] bf16
    int Nn, int Etot) {
  int wid = blockIdx.x * 4 + (threadIdx.x >> 6);
  if (wid >= Nn) return;
  int lane = threadIdx.x & 63;
  int g = lane >> 4;         // edge slot 0..3
  int c0 = (lane & 15) * 16; // 16 channels per lane

  f32x2 at2[8], xr2[8];
  {
    uint4 a4 = *reinterpret_cast<const uint4*>(att1 + c0);
    uint4 a5 = *reinterpret_cast<const uint4*>(att1 + c0 + 8);
    uint4 r4 = *reinterpret_cast<const uint4*>(C1 + (size_t)wid * 512 + 256 + c0);
    uint4 r5 = *reinterpret_cast<const uint4*>(C1 + (size_t)wid * 512 + 256 + c0 + 8);
    at2[0] = bf2x(a4.x); at2[1] = bf2x(a4.y); at2[2] = bf2x(a4.z); at2[3] = bf2x(a4.w);
    at2[4] = bf2x(a5.x); at2[5] = bf2x(a5.y); at2[6] = bf2x(a5.z); at2[7] = bf2x(a5.w);
    xr2[0] = bf2x(r4.x); xr2[1] = bf2x(r4.y); xr2[2] = bf2x(r4.z); xr2[3] = bf2x(r4.w);
    xr2[4] = bf2x(r5.x); xr2[5] = bf2x(r5.y); xr2[6] = bf2x(r5.z); xr2[7] = bf2x(r5.w);
  }

  float denom = 0.f;
  f32x2 acc2[8] = {};
  int beg = row_start[wid] + blkOff[wid >> 10];
  int end = row_start[wid + 1] + blkOff[(wid + 1) >> 10];
  if (beg < 0) beg = 0;
  if (end < beg || end - beg > Etot) end = beg;

  for (int base = beg; base < end; base += 64) {
    int cend = min(end, base + 64);
    int pl = base + lane;
    if (pl >= end) pl = end - 1;
    int s_pre = csr_src[pl];  // one coalesced load covers the whole chunk
#pragma unroll 2
    for (int i = base; i < cend; i += 4) {
      int p = i + g;               // p - base <= 63 always
      bool valid = p < cend;
      int s = __shfl(s_pre, p - base, 64);  // ds_bpermute, replaces global load
      if ((unsigned)s >= (unsigned)Nn) s = 0;
      const unsigned short* row = C1 + (size_t)s * 512 + c0;
      uint4 ra = *reinterpret_cast<const uint4*>(row);
      uint4 rb = *reinterpret_cast<const uint4*>(row + 8);
      f32x2 xl[8];
      xl[0] = bf2x(ra.x); xl[1] = bf2x(ra.y); xl[2] = bf2x(ra.z); xl[3] = bf2x(ra.w);
      xl[4] = bf2x(rb.x); xl[5] = bf2x(rb.y); xl[6] = bf2x(rb.z); xl[7] = bf2x(rb.w);
      f32x2 d2 = {0.f, 0.f};
#pragma unroll
      for (int k = 0; k < 8; k++) {
        f32x2 m = xl[k] + xr2[k];
        f32x2 l = __builtin_elementwise_max(m, m * 0.2f);  // leaky relu
        d2 += l * at2[k];
      }
      float dot = d2.x + d2.y;
      dot += dpp_mv<0xB1>(dot);  // xor1 within quad
      dot += dpp_mv<0x4E>(dot);  // xor2 -> head score in all 4 lanes of quad
      dot = fminf(fmaxf(dot, -60.f), 60.f);
      float wgt = valid ? __expf(dot) : 0.f;
      denom += wgt;
#pragma unroll
      for (int k = 0; k < 8; k++) acc2[k] += xl[k] * wgt;
    }
  }
  // merge the 4 edge slots (channel map depends only on lane&15)
#pragma unroll
  for (int off = 16; off <= 32; off <<= 1) {
    denom += __shfl_xor(denom, off, 64);
#pragma unroll
    for (int k = 0; k < 8; k++) {
      acc2[k].x += __shfl_xor(acc2[k].x, off, 64);
      acc2[k].y += __shfl_xor(acc2[k].y, off, 64);
    }
  }

  if (g == 0) {
    float inv = __builtin_amdgcn_rcpf(denom + 1e-16f);
    uint4 b4 = *reinterpret_cast<const uint4*>(bias1 + c0);
    uint4 b5 = *reinterpret_cast<const uint4*>(bias1 + c0 + 8);
    f32x2 bb[8] = {bf2x(b4.x), bf2x(b4.y), bf2x(b4.z), bf2x(b4.w),
                   bf2x(b5.x), bf2x(b5.y), bf2x(b5.z), bf2x(b5.w)};
    unsigned int od[8];
#pragma unroll
    for (int k = 0; k < 8; k++) {
      f32x2 xv = acc2[k] * inv + bb[k];
      float t0 = tanh_fast(xv.x);
      float t1 = tanh_fast(xv.y);
      od[k] = (unsigned int)f2b(t0) | ((unsigned int)f2b(t1) << 16);
    }
    uint4 o0 = {od[0], od[1], od[2], od[3]};
    uint4 o1 = {od[4], od[5], od[6], od[7]};
    *reinterpret_cast<uint4*>(H1 + (size_t)wid * 256 + c0) = o0;
    *reinterpret_cast<uint4*>(H1 + (size_t)wid * 256 + c0 + 8) = o1;
  }
}

// ---------------- layer-2 aggregation: 16 edges/wave-iteration + log_softmax ----------------
// edge slot = lane>>2 (16 slots), each lane owns 4 channels (cg = (lane&3)*4).
// Score reduce over slot = DPP xor1/xor2; slot merge = DPP row_ror:4/8 (channel-
// preserving) + shfl 16/32. csr_src hoisted like agg1. Avg degree ~9 -> 1 iter.
__global__ __launch_bounds__(256) void agg2_kernel(
    const float* __restrict__ C2,             // [N,32]: 0-15 xl2, 16-31 xr2
    const unsigned short* __restrict__ att2,  // [16]
    const unsigned short* __restrict__ bias2, // [16]
    const int* __restrict__ row_start, const int* __restrict__ blkOff,
    const int* __restrict__ csr_src,
    float* __restrict__ out,                  // [2*N*16] f32 (o, log_softmax)
    int Nn, int Etot) {
  int wid = blockIdx.x * 4 + (threadIdx.x >> 6);
  if (wid >= Nn) return;
  int lane = threadIdx.x & 63;
  int eslot = lane >> 2;
  int cg = (lane & 3) * 4;

  float at[4], xr[4];
  {
    ushort4 a4 = *reinterpret_cast<const ushort4*>(att2 + cg);
    at[0] = b2f(a4.x); at[1] = b2f(a4.y); at[2] = b2f(a4.z); at[3] = b2f(a4.w);
    float4 r4 = *reinterpret_cast<const float4*>(C2 + (size_t)wid * 32 + 16 + cg);
    xr[0] = r4.x; xr[1] = r4.y; xr[2] = r4.z; xr[3] = r4.w;
  }

  float denom = 0.f;
  float acc[4] = {0.f, 0.f, 0.f, 0.f};
  int beg = row_start[wid] + blkOff[wid >> 10];
  int end = row_start[wid + 1] + blkOff[(wid + 1) >> 10];
  if (beg < 0) beg = 0;
  if (end < beg || end - beg > Etot) end = beg;

  for (int base = beg; base < end; base += 64) {
    int cend = min(end, base + 64);
    int pl = base + lane;
    if (pl >= end) pl = end - 1;
    int s_pre = csr_src[pl];
    for (int i = base; i < cend; i += 16) {
      int p = i + eslot;  // p - base <= 63 always
      bool valid = p < cend;
      int s = __shfl(s_pre, p - base, 64);
      if ((unsigned)s >= (unsigned)Nn) s = 0;
      float4 x4 = *reinterpret_cast<const float4*>(C2 + (size_t)s * 32 + cg);
      float xl[4] = {x4.x, x4.y, x4.z, x4.w};
      float dot = 0.f;
#pragma unroll
      for (int k = 0; k < 4; k++) {
        float m = xl[k] + xr[k];
        float l = fmaxf(m, 0.2f * m);
        dot = fmaf(l, at[k], dot);
      }
      dot += dpp_mv<0xB1>(dot);  // xor1
      dot += dpp_mv<0x4E>(dot);  // xor2 -> edge score in all 4 lanes of slot
      dot = fminf(fmaxf(dot, -60.f), 60.f);
      float wgt = valid ? __expf(dot) : 0.f;
      denom += wgt;
#pragma unroll
      for (int k = 0; k < 4; k++) acc[k] = fmaf(wgt, xl[k], acc[k]);
    }
  }
  // merge 4 slots within each 16-lane row (rotations preserve lane&3 channel map)
  denom += dpp_mv<0x124>(denom);
  denom += dpp_mv<0x128>(denom);
#pragma unroll
  for (int k = 0; k < 4; k++) {
    acc[k] += dpp_mv<0x124>(acc[k]);
    acc[k] += dpp_mv<0x128>(acc[k]);
  }
  // merge the 4 rows
#pragma unroll
  for (int off = 16; off <= 32; off <<= 1) {
    denom += __shfl_xor(denom, off, 64);
#pragma unroll
    for (int k = 0; k < 4; k++) acc[k] += __shfl_xor(acc[k], off, 64);
  }

  float inv = __builtin_amdgcn_rcpf(denom + 1e-16f);
  ushort4 b4 = *reinterpret_cast<const ushort4*>(bias2 + cg);
  float bb[4] = {b2f(b4.x), b2f(b4.y), b2f(b4.z), b2f(b4.w)};
  float o[4];
#pragma unroll
  for (int k = 0; k < 4; k++) {
    o[k] = acc[k] * inv + bb[k];
    if (!(o[k] == o[k])) o[k] = 0.f;
  }
  // log_softmax over 16 channels (4 per lane across the 4 channel-lanes of a quad)
  float mx = fmaxf(fmaxf(o[0], o[1]), fmaxf(o[2], o[3]));
  mx = fmaxf(mx, dpp_mv<0xB1>(mx));
  mx = fmaxf(mx, dpp_mv<0x4E>(mx));
  float se = 0.f;
#pragma unroll
  for (int k = 0; k < 4; k++) se += __expf(o[k] - mx);
  se += dpp_mv<0xB1>(se);
  se += dpp_mv<0x4E>(se);
  float ls = logf(se);
  if (lane < 4) {
    float4 vo = {o[0], o[1], o[2], o[3]};
    float4 vl = {o[0] - mx - ls, o[1] - mx - ls, o[2] - mx - ls, o[3] - mx - ls};
    *reinterpret_cast<float4*>(out + (size_t)wid * 16 + cg) = vo;
    *reinterpret_cast<float4*>(out + (size_t)Nn * 16 + (size_t)wid * 16 + cg) = vl;
  }
}

extern "C" void kernel_launch(void* const* d_in, const int* in_sizes, int n_in,
                              void* d_out, int out_size, void* d_ws, size_t ws_size,
                              hipStream_t stream) {
  const void* x_raw = d_in[0];
  const int* ei     = (const int*)d_in[1];

  const int M = in_sizes[0] / 256;  // nodes (50000)
  const int E = in_sizes[1] / 2;    // raw edges (400000)
  const int TOT = E + M;            // edges incl. self-loops
  const int NX = M * 256;

  char* ws = (char*)d_ws;
  size_t off = 0;
  auto alloc = [&](size_t bytes) -> void* {
    void* p = ws + off;
    off = (off + bytes + 255) & ~(size_t)255;
    return p;
  };
  int*            flag   = (int*)alloc(4);
  unsigned short* Pc     = (unsigned short*)alloc((size_t)P_TOT * 2);
  unsigned short* Xc     = (unsigned short*)alloc((size_t)NX * 2);
  unsigned short* WT1    = (unsigned short*)alloc((size_t)512 * 256 * 2);
  unsigned short* WT2    = (unsigned short*)alloc((size_t)32 * 256 * 2);
  int*            cnt    = (int*)alloc((size_t)M * 4);
  int*            cursor = (int*)alloc((size_t)M * 4);
  int*            row_start = (int*)alloc((size_t)(M + 1) * 4);
  int*            csr_src   = (int*)alloc((size_t)TOT * 4);
  int*            blkTot = (int*)alloc(64 * 4);
  int*            blkOff = (int*)alloc(65 * 4);
  float*          C2     = (float*)alloc((size_t)M * 32 * 4);
  unsigned short* C1     = (unsigned short*)alloc((size_t)M * 512 * 2);
  const size_t need = off;
  (void)n_in;
  // H1 aliases Xc: gemm1 is the last reader of Xc (or reads x_raw directly);
  // agg1 writes H1 later.
  unsigned short* H1 = Xc;

  if (ws_size < need) {
    hipMemsetAsync(d_out, 0, (size_t)out_size * 4, stream);
    return;
  }

  unsigned short* bl1c   = Pc + 65536;
  unsigned short* br1c   = Pc + 131328;
  unsigned short* att1c  = Pc + 131584;
  unsigned short* bias1c = Pc + 131840;
  unsigned short* bl2c   = Pc + 136192;
  unsigned short* br2c   = Pc + 140304;
  unsigned short* att2c  = Pc + 140320;
  unsigned short* bias2c = Pc + 140336;

  hipMemsetAsync(cnt, 0, (size_t)M * 4, stream);

  probe_kernel<<<1, 64, 0, stream>>>((const unsigned short*)x_raw, flag);

  // fused: conv_x | count | conv_params
  const int nb_convx = (NX / 4 + 255) / 256;
  const int nb_count = (TOT + 255) / 256;
  const int nb_convp = (P_TOT + 255) / 256;
  fused_pre_kernel<<<nb_convx + nb_count + nb_convp, 256, 0, stream>>>(
      x_raw, Xc, flag, NX, ei, E, M, cnt,
      d_in[2], d_in[3], d_in[4], d_in[5], d_in[6], d_in[7], d_in[8], d_in[9],
      d_in[10], d_in[11], d_in[12], d_in[13], Pc, nb_convx, nb_count);

  // fused: scan1 (+cursor zero) | transpose
  const int nb_scan = (M + 1023) / 1024;
  const int nb_tr = (512 * 256 + 32 * 256 + 1023) / 1024;
  fused_mid_kernel<<<nb_scan + nb_tr, 1024, 0, stream>>>(cnt, row_start, blkTot,
                                                         cursor, M, nb_scan, Pc, WT1, WT2);

  scan2_kernel<<<1, 64, 0, stream>>>(blkTot, blkOff, nb_scan, row_start, M, TOT);

  fill_kernel<<<(TOT + 255) / 256, 256, 0, stream>>>(ei, E, M, row_start, blkOff,
                                                     cursor, csr_src);

  gemm1_kernel<<<(M + 63) / 64, 256, 0, stream>>>(Xc, (const unsigned short*)x_raw, flag,
                                                  WT1, bl1c, br1c, C1, M);

  agg1_kernel<<<(M + 3) / 4, 256, 0, stream>>>(C1, att1c, bias1c, row_start, blkOff,
                                               csr_src, H1, M, TOT);

  gemm2_kernel<<<(M + 63) / 64, 256, 0, stream>>>(H1, WT2, bl2c, br2c, C2, M);

  agg2_kernel<<<(M + 3) / 4, 256, 0, stream>>>(C2, att2c, bias2c, row_start, blkOff,
                                               csr_src, (float*)d_out, M, TOT);
}

// Round 7
// 274.245 us; speedup vs baseline: 1.1536x; 1.1536x over previous
//
#include <hip/hip_runtime.h>

typedef __bf16 bfv8 __attribute__((ext_vector_type(8)));
typedef float f32x4 __attribute__((ext_vector_type(4)));
typedef float f32x2 __attribute__((ext_vector_type(2)));
typedef short shortv8 __attribute__((ext_vector_type(8)));
typedef unsigned short usv8 __attribute__((ext_vector_type(8)));

__device__ __forceinline__ float b2f(unsigned short u) {
  unsigned int v = ((unsigned int)u) << 16;
  float f;
  __builtin_memcpy(&f, &v, 4);
  return f;
}
__device__ __forceinline__ unsigned short f2b(float f) {
  unsigned int u;
  __builtin_memcpy(&u, &f, 4);
  u += 0x7fffu + ((u >> 16) & 1u);
  return (unsigned short)(u >> 16);
}

// unpack a dword holding two bf16 (lo = even channel, hi = odd channel) to float2
__device__ __forceinline__ f32x2 bf2x(unsigned int u) {
  f32x2 r;
  r.x = __builtin_bit_cast(float, u << 16);
  r.y = __builtin_bit_cast(float, u & 0xffff0000u);
  return r;
}

// DPP neighbor fetch (compile-time control); all lanes active at every call site.
// 0xB1 = quad_perm xor1, 0x4E = quad_perm xor2, 0x141 = row_half_mirror,
// 0x124 = row_ror:4, 0x128 = row_ror:8
template <int CTRL>
__device__ __forceinline__ float dpp_mv(float x) {
  int xi = __builtin_bit_cast(int, x);
  int yi = __builtin_amdgcn_update_dpp(0, xi, CTRL, 0xf, 0xf, true);
  return __builtin_bit_cast(float, yi);
}

__device__ __forceinline__ float tanh_fast(float x) {
  // tanh(x) = 1 - 2/(e^{2x}+1); rcp is ~1ulp, output is bf16 -> negligible
  float e2 = __expf(2.f * x);
  float r = __builtin_amdgcn_rcpf(e2 + 1.f);
  float th = fmaf(-2.f, r, 1.f);
  if (!(th == th)) th = 0.f;
  return th;
}

// ---------------- in-block dtype probe: every block classifies x itself -----
// Reads x[0:4096] as ushorts (8KB, L2-broadcast-hot). f32-as-bf16 shows ~48%
// absurd exponents. All 256 threads must call (contains __syncthreads).
__device__ __forceinline__ int block_probe(const unsigned short* __restrict__ xs,
                                           int* __restrict__ red) {
  int t = threadIdx.x;
  const uint4* p = reinterpret_cast<const uint4*>(xs) + t * 2;
  uint4 a = p[0], b = p[1];
  unsigned int w[8] = {a.x, a.y, a.z, a.w, b.x, b.y, b.z, b.w};
  int cnt = 0;
#pragma unroll
  for (int k = 0; k < 8; k++) {
    if ((((w[k] & 0xffffu) >> 7) & 0xffu) >= 0x86u) cnt++;
    if (((w[k] >> 23) & 0xffu) >= 0x86u) cnt++;
  }
#pragma unroll
  for (int off = 1; off < 64; off <<= 1) cnt += __shfl_xor(cnt, off, 64);
  if ((t & 63) == 0) red[t >> 6] = cnt;
  __syncthreads();
  return (red[0] + red[1] + red[2] + red[3]) > 100 ? 1 : 0;
}

// ---------------- fused: conv_x | count | conv_params (all 256-thread) ----------------
// conv_x only does work when flag==1 (f32 input); bf16 inputs are read in place
// by gemm1. Block 0 publishes flag to ws for gemm1 (runs later).
// Wl1@0 bl1@65536 Wr1@65792 br1@131328 att1@131584 bias1@131840
// Wl2@132096 bl2@136192 Wr2@136208 br2@140304 att2@140320 bias2@140336  total 140352
#define P_TOT 140352
__global__ __launch_bounds__(256) void fused_pre_kernel(
    const void* __restrict__ x, unsigned short* __restrict__ Xc,
    int* __restrict__ flagw, int NX,
    const int* __restrict__ ei, int E, int Nn, int* __restrict__ cnt,
    const void* p0, const void* p1, const void* p2, const void* p3,
    const void* p4, const void* p5, const void* p6, const void* p7,
    const void* p8, const void* p9, const void* p10, const void* p11,
    unsigned short* __restrict__ Pc, int nb_convx, int nb_count) {
  __shared__ int red[4];
  int b = blockIdx.x;
  int t = threadIdx.x;
  if (b < nb_convx) {
    // ---- conv_x (f32 -> bf16 only; bf16 passthrough handled in gemm1) ----
    int flag = block_probe((const unsigned short*)x, red);
    if (b == 0 && t == 0) *flagw = flag;
    if (!flag) return;
    int i = (b * 256 + t) * 4;
    if (i >= NX) return;
    float4 f = *reinterpret_cast<const float4*>((const float*)x + i);
    ushort4 o;
    o.x = f2b(f.x); o.y = f2b(f.y); o.z = f2b(f.z); o.w = f2b(f.w);
    *reinterpret_cast<ushort4*>(Xc + i) = o;
  } else if (b < nb_convx + nb_count) {
    // ---- count (degree histogram incl. self-loops) ----
    int i = (b - nb_convx) * 256 + t;
    int total = E + Nn;
    if (i >= total) return;
    int d = (i < E) ? ei[E + i] : (i - E);
    if ((unsigned)d >= (unsigned)Nn) d = 0;
    atomicAdd(&cnt[d], 1);
  } else {
    // ---- conv_params ----
    int flag = block_probe((const unsigned short*)x, red);
    int i = (b - nb_convx - nb_count) * 256 + t;
    if (i >= P_TOT) return;
    const int offs[13] = {0, 65536, 65792, 131328, 131584, 131840, 132096,
                          136192, 136208, 140304, 140320, 140336, P_TOT};
    const void* ptrs[12] = {p0, p1, p2, p3, p4, p5, p6, p7, p8, p9, p10, p11};
    int k = 0;
    while (i >= offs[k + 1]) k++;
    int local = i - offs[k];
    unsigned short v;
    if (flag) v = f2b(((const float*)ptrs[k])[local]);
    else v = ((const unsigned short*)ptrs[k])[local];
    Pc[i] = v;
  }
}

// ---------------- fused: scan1 (+cursor zero) | merged W transposes (1024-thread) ----
__global__ __launch_bounds__(1024) void fused_mid_kernel(
    const int* __restrict__ cnt, int* __restrict__ row_start, int* __restrict__ blkTot,
    int* __restrict__ cursor, int Nn, int nb_scan,
    const unsigned short* __restrict__ Pc,
    unsigned short* __restrict__ WT1, unsigned short* __restrict__ WT2) {
  int b = blockIdx.x;
  int t = threadIdx.x;
  if (b < nb_scan) {
    // ---- scan1: block-local exclusive prefix over degree counts ----
    __shared__ int buf[1024];
    int i = b * 1024 + t;
    int v = (i < Nn) ? cnt[i] : 0;
    buf[t] = v;
    if (i < Nn) cursor[i] = 0;  // fold cursor memset in here (fill runs later)
    __syncthreads();
    for (int off = 1; off < 1024; off <<= 1) {
      int x = (t >= off) ? buf[t - off] : 0;
      __syncthreads();
      buf[t] += x;
      __syncthreads();
    }
    if (i < Nn) row_start[i] = buf[t] - v;  // block-local exclusive
    if (t == 1023) blkTot[b] = buf[1023];
  } else {
    // ---- transpose: WT1[n][k]=W1[k][n], WT2[n][k]=W2[k][n] ----
    int idx = (b - nb_scan) * 1024 + t;
    if (idx < 512 * 256) {
      int n = idx >> 8, k = idx & 255;
      WT1[idx] = (n < 256) ? Pc[0 + k * 256 + n]               // Wl1
                           : Pc[65792 + k * 256 + (n - 256)];  // Wr1
    } else {
      int j = idx - 512 * 256;
      if (j < 32 * 256) {
        int n = j >> 8, k = j & 255;
        WT2[j] = (n < 16) ? Pc[132096 + k * 16 + n]            // Wl2
                          : Pc[136208 + k * 16 + (n - 16)];    // Wr2
      }
    }
  }
}

// ---------------- fill (absorbs scan2): scatter src ids to CSR ----------------
// Each wave recomputes the 64-wide prefix over blkTot in-register (6 shfl_up)
// and resolves blkOff[d>>10] via one __shfl. Block 0 publishes blkOff[] and
// row_start[Nn] for the agg kernels. No early returns before wave shuffles.
__global__ __launch_bounds__(256) void fill_kernel(const int* __restrict__ ei, int E, int Nn,
                                                   int* __restrict__ row_start,
                                                   const int* __restrict__ blkTot, int nbscan,
                                                   int* __restrict__ cursor,
                                                   int* __restrict__ csr_src,
                                                   int* __restrict__ blkOff) {
  int lane = threadIdx.x & 63;
  int total = E + Nn;
  int v = (lane < nbscan) ? blkTot[lane] : 0;
  int s = v;
#pragma unroll
  for (int off = 1; off < 64; off <<= 1) {
    int u = __shfl_up(s, off, 64);
    if (lane >= off) s += u;
  }
  int excl = s - v;  // lane l holds exclusive prefix for scan-block l

  if (blockIdx.x == 0 && threadIdx.x < 64) {
    blkOff[lane] = excl;
    if (lane == 63) blkOff[64] = s;
    int idx = Nn >> 10;
    int bo = (idx >= 64) ? __shfl(s, 63, 64) : __shfl(excl, idx, 64);
    if (lane == 0) row_start[Nn] = total - bo;  // row_start[Nn]+blkOff[idx]==total
  }

  int i = blockIdx.x * 256 + threadIdx.x;
  bool act = i < total;
  int sv = 0, d = 0;
  if (act) {
    if (i < E) { sv = ei[i]; d = ei[E + i]; } else { sv = i - E; d = i - E; }
    if ((unsigned)d >= (unsigned)Nn) d = 0;
    if ((unsigned)sv >= (unsigned)Nn) sv = 0;
  }
  int bo_d = __shfl(excl, d >> 10, 64);  // all lanes live (no early return)
  if (act) {
    int pos = row_start[d] + bo_d + atomicAdd(&cursor[d], 1);
    if ((unsigned)pos < (unsigned)total) csr_src[pos] = sv;
  }
}

// ---------------- GEMM1: C[M,512] = X[M,256] @ [Wl1|Wr1] + bias (bf16 out)
// X tile (128 rows) staged coalesced in LDS (dbuf, XOR seg-swizzle); WT direct
// from L2. XCD co-location: the 4 n-siblings of an m-group get blockIdx values
// {b, b+8, b+16, b+24} -> same bid%8 -> same XCD -> X slab fetched once (r4:
// consecutive-sibling layout doubled FETCH because per-XCD L2s don't share).
// LDS 32KB (epilogue = two 32-row per-warp half-passes) -> 5 blocks/CU.
__global__ __launch_bounds__(256) void gemm1_kernel(
    const unsigned short* __restrict__ Xc,     // bf16 [M,256] (converted)
    const unsigned short* __restrict__ x_raw,  // raw input (bf16 case)
    const int* __restrict__ flagp,
    const unsigned short* __restrict__ WT,     // bf16 [512,256]
    const unsigned short* __restrict__ bl, const unsigned short* __restrict__ br,
    unsigned short* __restrict__ C, int M) {
  __shared__ unsigned short smem[16384];  // 32768B: K-loop 2x8192; epilogue 4x2304
  const unsigned short* X = (*flagp) ? Xc : x_raw;
  const int t = threadIdx.x;
  const int lane = t & 63;
  const int w = t >> 6;
  const int quad = lane >> 4;
  const int l16 = lane & 15;

  // XCD co-location remap: grid = 4*G blocks; within each 32-block super, the
  // 8 XCD slots each own one m-group, and the 4 slots {xcd, xcd+8, xcd+16,
  // xcd+24} are that group's n-siblings.
  const int G = (M + 127) >> 7;
  const int nfull = (G >> 3) << 5;
  int bid = blockIdx.x, grp, n_blk;
  if (bid < nfull) {
    grp = (bid >> 5) * 8 + (bid & 7);
    n_blk = (bid >> 3) & 3;
  } else {
    int r = bid - nfull;
    grp = (G & ~7) + (r >> 2);
    n_blk = r & 3;
  }
  const int m_blk = grp * 128;
  const int m_base = m_blk + (w >> 1) * 64;
  const int n_base = n_blk * 128 + (w & 1) * 64;

  const int st_row = t >> 3;  // 0..31
  const int st_seg = t & 7;   // 0..7

  f32x4 acc[4][4];
#pragma unroll
  for (int i = 0; i < 4; i++)
#pragma unroll
    for (int j = 0; j < 4; j++) acc[i][j] = (f32x4){0.f, 0.f, 0.f, 0.f};

  shortv8 st[4];
#pragma unroll
  for (int i = 0; i < 4; i++) {
    int gr = m_blk + st_row + 32 * i;
    if (gr >= M) gr = M - 1;
    st[i] = *reinterpret_cast<const shortv8*>(X + (size_t)gr * 256 + st_seg * 8);
  }
#pragma unroll
  for (int i = 0; i < 4; i++) {
    int row = st_row + 32 * i;
    *reinterpret_cast<shortv8*>(smem + row * 64 + ((st_seg ^ (row & 7)) * 8)) = st[i];
  }
  __syncthreads();

#pragma unroll
  for (int c = 0; c < 4; c++) {
    if (c < 3) {
#pragma unroll
      for (int i = 0; i < 4; i++) {
        int gr = m_blk + st_row + 32 * i;
        if (gr >= M) gr = M - 1;
        st[i] = *reinterpret_cast<const shortv8*>(X + (size_t)gr * 256 + (c + 1) * 64 +
                                                  st_seg * 8);
      }
    }
    const unsigned short* bb = smem + (c & 1) * 8192;
#pragma unroll
    for (int sub = 0; sub < 2; sub++) {
      bfv8 a[4], b[4];
      int seg_r = sub * 4 + quad;  // 0..7
#pragma unroll
      for (int i = 0; i < 4; i++) {
        int lrow = (w >> 1) * 64 + 16 * i + l16;  // 0..127 within tile
        a[i] = *reinterpret_cast<const bfv8*>(bb + lrow * 64 + ((seg_r ^ (lrow & 7)) * 8));
      }
#pragma unroll
      for (int j = 0; j < 4; j++) {
        int col = n_base + 16 * j + l16;
        b[j] = *reinterpret_cast<const bfv8*>(WT + (size_t)col * 256 + c * 64 + sub * 32 +
                                              quad * 8);
      }
#pragma unroll
      for (int i = 0; i < 4; i++)
#pragma unroll
        for (int j = 0; j < 4; j++)
          acc[i][j] = __builtin_amdgcn_mfma_f32_16x16x32_bf16(a[i], b[j], acc[i][j], 0, 0, 0);
    }
    if (c < 3) {
      int buf = (c + 1) & 1;
#pragma unroll
      for (int i = 0; i < 4; i++) {
        int row = st_row + 32 * i;
        *reinterpret_cast<shortv8*>(smem + buf * 8192 + row * 64 +
                                    ((st_seg ^ (row & 7)) * 8)) = st[i];
      }
      __syncthreads();
    }
  }

  __syncthreads();  // all warps done reading K-loop buffers before epilogue reuse
  // epilogue: two 32-row half-passes through per-warp-private LDS (2304 shorts
  // each, 9216 total). Same-wave RAW on LDS needs no barrier.
  unsigned short* lt = smem + w * 2304;
#pragma unroll
  for (int h = 0; h < 2; h++) {
#pragma unroll
    for (int j = 0; j < 4; j++) {
      int col = n_base + 16 * j + l16;
      float bias = (col < 256) ? b2f(bl[col]) : b2f(br[col - 256]);
#pragma unroll
      for (int i2 = 0; i2 < 2; i2++) {
        int i = 2 * h + i2;
#pragma unroll
        for (int r = 0; r < 4; r++)
          lt[(16 * i2 + quad * 4 + r) * 72 + 16 * j + l16] = f2b(acc[i][j][r] + bias);
      }
    }
#pragma unroll
    for (int pass = 0; pass < 4; pass++) {
      int row = pass * 8 + (lane >> 3);
      int colg = (lane & 7) * 8;
      shortv8 v = *reinterpret_cast<const shortv8*>(lt + row * 72 + colg);
      int grow = m_base + 32 * h + row;
      if (grow < M)
        *reinterpret_cast<shortv8*>(C + (size_t)grow * 512 + n_base + colg) = v;
    }
  }
}

// ---------------- GEMM2: C2[M,32] = H[M,256] @ [Wl2|Wr2] + bias (f32 out)
// 64-row tiles, H staged coalesced in 16KB dbuf LDS, WT2 (16KB, L2-hot) direct.
__global__ __launch_bounds__(256) void gemm2_kernel(
    const unsigned short* __restrict__ H, const unsigned short* __restrict__ WT,
    const unsigned short* __restrict__ bl, const unsigned short* __restrict__ br,
    float* __restrict__ C, int M) {
  __shared__ unsigned short smem[8192];  // 2 x (64 rows x 64 k), XOR seg-swizzle
  const int t = threadIdx.x;
  const int lane = t & 63;
  const int w = t >> 6;
  const int quad = lane >> 4;
  const int l16 = lane & 15;
  const int m_blk = blockIdx.x * 64;
  const int wrow = w * 16;  // warp's 16-row slice

  const int st_row = t >> 2;  // 0..63
  const int st_seg = t & 3;   // covers segs st_seg and st_seg+4

  f32x4 acc[2];
  acc[0] = (f32x4){0.f, 0.f, 0.f, 0.f};
  acc[1] = (f32x4){0.f, 0.f, 0.f, 0.f};

  int gr = m_blk + st_row;
  if (gr >= M) gr = M - 1;
  const unsigned short* hrow = H + (size_t)gr * 256;

  shortv8 st0 = *reinterpret_cast<const shortv8*>(hrow + st_seg * 8);
  shortv8 st1 = *reinterpret_cast<const shortv8*>(hrow + st_seg * 8 + 32);
  *reinterpret_cast<shortv8*>(smem + st_row * 64 + ((st_seg ^ (st_row & 7)) * 8)) = st0;
  *reinterpret_cast<shortv8*>(smem + st_row * 64 + (((st_seg + 4) ^ (st_row & 7)) * 8)) = st1;
  __syncthreads();

#pragma unroll
  for (int c = 0; c < 4; c++) {
    if (c < 3) {
      st0 = *reinterpret_cast<const shortv8*>(hrow + (c + 1) * 64 + st_seg * 8);
      st1 = *reinterpret_cast<const shortv8*>(hrow + (c + 1) * 64 + st_seg * 8 + 32);
    }
    const unsigned short* bb = smem + (c & 1) * 4096;
#pragma unroll
    for (int sub = 0; sub < 2; sub++) {
      int seg_r = sub * 4 + quad;
      int lrow = wrow + l16;
      bfv8 a = *reinterpret_cast<const bfv8*>(bb + lrow * 64 + ((seg_r ^ (lrow & 7)) * 8));
      bfv8 b[2];
#pragma unroll
      for (int j = 0; j < 2; j++) {
        int col = 16 * j + l16;
        b[j] = *reinterpret_cast<const bfv8*>(WT + (size_t)col * 256 + c * 64 + sub * 32 +
                                              quad * 8);
      }
#pragma unroll
      for (int j = 0; j < 2; j++)
        acc[j] = __builtin_amdgcn_mfma_f32_16x16x32_bf16(a, b[j], acc[j], 0, 0, 0);
    }
    if (c < 3) {
      int buf = (c + 1) & 1;
      *reinterpret_cast<shortv8*>(smem + buf * 4096 + st_row * 64 +
                                  ((st_seg ^ (st_row & 7)) * 8)) = st0;
      *reinterpret_cast<shortv8*>(smem + buf * 4096 + st_row * 64 +
                                  (((st_seg + 4) ^ (st_row & 7)) * 8)) = st1;
      __syncthreads();
    }
  }

#pragma unroll
  for (int j = 0; j < 2; j++) {
    int col = 16 * j + l16;
    float bias = (j == 0) ? b2f(bl[l16]) : b2f(br[l16]);
#pragma unroll
    for (int r = 0; r < 4; r++) {
      int row = m_blk + wrow + quad * 4 + r;
      if (row < M) C[(size_t)row * 32 + col] = acc[j][r] + bias;
    }
  }
}

// ---------------- layer-1 aggregation: 2 edges/wave-iteration + tanh ----------------
// lanes 0-31 = edge A, lanes 32-63 = edge B; each lane owns 8 channels
// (c0 = (lane&31)*8) processed as 4x float2 (V_PK_* packed f32).
// Head = 8-lane group; score reduce = DPP xor1/xor2/half_mirror (no LDS pipe).
// csr_src indices for up to 64 edges hoisted into registers. VGPR 32 / occ 64%
// is the sweet spot (r6: 16ch/lane variant dropped occ to 44% and regressed).
__global__ __launch_bounds__(256) void agg1_kernel(
    const unsigned short* __restrict__ C1,    // [N,512]: 0-255 xl, 256-511 xr
    const unsigned short* __restrict__ att1,  // [256]
    const unsigned short* __restrict__ bias1, // [256]
    const int* __restrict__ row_start, const int* __restrict__ blkOff,
    const int* __restrict__ csr_src,
    unsigned short* __restrict__ H1,          // [N,256] bf16
    int Nn, int Etot) {
  int wid = blockIdx.x * 4 + (threadIdx.x >> 6);
  if (wid >= Nn) return;
  int lane = threadIdx.x & 63;
  int half = lane >> 5;
  int c0 = (lane & 31) * 8;

  f32x2 at2[4], xr2[4];
  {
    uint4 a4 = *reinterpret_cast<const uint4*>(att1 + c0);
    uint4 r4 = *reinterpret_cast<const uint4*>(C1 + (size_t)wid * 512 + 256 + c0);
    at2[0] = bf2x(a4.x); at2[1] = bf2x(a4.y); at2[2] = bf2x(a4.z); at2[3] = bf2x(a4.w);
    xr2[0] = bf2x(r4.x); xr2[1] = bf2x(r4.y); xr2[2] = bf2x(r4.z); xr2[3] = bf2x(r4.w);
  }

  float denom = 0.f;
  f32x2 acc2[4] = {};
  int beg = row_start[wid] + blkOff[wid >> 10];
  int end = row_start[wid + 1] + blkOff[(wid + 1) >> 10];
  if (beg < 0) beg = 0;
  if (end < beg || end - beg > Etot) end = beg;

  for (int base = beg; base < end; base += 64) {
    int cend = min(end, base + 64);
    int pl = base + lane;
    if (pl >= end) pl = end - 1;
    int s_pre = csr_src[pl];  // one coalesced load covers the whole chunk
#pragma unroll 2
    for (int i = base; i < cend; i += 2) {
      int p = i + half;             // p - base <= 63 always
      bool valid = p < cend;
      int s = __shfl(s_pre, p - base, 64);  // ds_bpermute, replaces global load
      if ((unsigned)s >= (unsigned)Nn) s = 0;
      uint4 rw = *reinterpret_cast<const uint4*>(C1 + (size_t)s * 512 + c0);
      f32x2 xl0 = bf2x(rw.x), xl1 = bf2x(rw.y), xl2 = bf2x(rw.z), xl3 = bf2x(rw.w);
      f32x2 m0 = xl0 + xr2[0], m1 = xl1 + xr2[1];
      f32x2 m2 = xl2 + xr2[2], m3 = xl3 + xr2[3];
      f32x2 l0 = __builtin_elementwise_max(m0, m0 * 0.2f);  // leaky relu
      f32x2 l1 = __builtin_elementwise_max(m1, m1 * 0.2f);
      f32x2 l2 = __builtin_elementwise_max(m2, m2 * 0.2f);
      f32x2 l3 = __builtin_elementwise_max(m3, m3 * 0.2f);
      f32x2 d2 = l0 * at2[0];
      d2 += l1 * at2[1];
      d2 += l2 * at2[2];
      d2 += l3 * at2[3];
      float dot = d2.x + d2.y;
      dot += dpp_mv<0xB1>(dot);   // xor1 within quad
      dot += dpp_mv<0x4E>(dot);   // xor2 within quad
      dot += dpp_mv<0x141>(dot);  // half_mirror: cross-quad within 8-group (quads uniform)
      dot = fminf(fmaxf(dot, -60.f), 60.f);
      float wgt = valid ? __expf(dot) : 0.f;
      denom += wgt;
      acc2[0] += xl0 * wgt;
      acc2[1] += xl1 * wgt;
      acc2[2] += xl2 * wgt;
      acc2[3] += xl3 * wgt;
    }
  }
  // merge halves
  denom += __shfl_xor(denom, 32, 64);
#pragma unroll
  for (int k = 0; k < 4; k++) {
    acc2[k].x += __shfl_xor(acc2[k].x, 32, 64);
    acc2[k].y += __shfl_xor(acc2[k].y, 32, 64);
  }

  if (half == 0) {
    float inv = __builtin_amdgcn_rcpf(denom + 1e-16f);
    uint4 b4 = *reinterpret_cast<const uint4*>(bias1 + c0);
    f32x2 bb[4] = {bf2x(b4.x), bf2x(b4.y), bf2x(b4.z), bf2x(b4.w)};
    uint4 o;
    unsigned int od[4];
#pragma unroll
    for (int k = 0; k < 4; k++) {
      f32x2 xv = acc2[k] * inv + bb[k];
      float t0 = tanh_fast(xv.x);
      float t1 = tanh_fast(xv.y);
      od[k] = (unsigned int)f2b(t0) | ((unsigned int)f2b(t1) << 16);
    }
    o.x = od[0]; o.y = od[1]; o.z = od[2]; o.w = od[3];
    *reinterpret_cast<uint4*>(H1 + (size_t)wid * 256 + c0) = o;
  }
}

// ---------------- layer-2 aggregation: 16 edges/wave-iteration + log_softmax ----------------
// edge slot = lane>>2 (16 slots), each lane owns 4 channels (cg = (lane&3)*4).
// Score reduce over slot = DPP xor1/xor2; slot merge = DPP row_ror:4/8 (channel-
// preserving) + shfl 16/32. csr_src hoisted like agg1. Avg degree ~9 -> 1 iter.
__global__ __launch_bounds__(256) void agg2_kernel(
    const float* __restrict__ C2,             // [N,32]: 0-15 xl2, 16-31 xr2
    const unsigned short* __restrict__ att2,  // [16]
    const unsigned short* __restrict__ bias2, // [16]
    const int* __restrict__ row_start, const int* __restrict__ blkOff,
    const int* __restrict__ csr_src,
    float* __restrict__ out,                  // [2*N*16] f32 (o, log_softmax)
    int Nn, int Etot) {
  int wid = blockIdx.x * 4 + (threadIdx.x >> 6);
  if (wid >= Nn) return;
  int lane = threadIdx.x & 63;
  int eslot = lane >> 2;
  int cg = (lane & 3) * 4;

  float at[4], xr[4];
  {
    ushort4 a4 = *reinterpret_cast<const ushort4*>(att2 + cg);
    at[0] = b2f(a4.x); at[1] = b2f(a4.y); at[2] = b2f(a4.z); at[3] = b2f(a4.w);
    float4 r4 = *reinterpret_cast<const float4*>(C2 + (size_t)wid * 32 + 16 + cg);
    xr[0] = r4.x; xr[1] = r4.y; xr[2] = r4.z; xr[3] = r4.w;
  }

  float denom = 0.f;
  float acc[4] = {0.f, 0.f, 0.f, 0.f};
  int beg = row_start[wid] + blkOff[wid >> 10];
  int end = row_start[wid + 1] + blkOff[(wid + 1) >> 10];
  if (beg < 0) beg = 0;
  if (end < beg || end - beg > Etot) end = beg;

  for (int base = beg; base < end; base += 64) {
    int cend = min(end, base + 64);
    int pl = base + lane;
    if (pl >= end) pl = end - 1;
    int s_pre = csr_src[pl];
    for (int i = base; i < cend; i += 16) {
      int p = i + eslot;  // p - base <= 63 always
      bool valid = p < cend;
      int s = __shfl(s_pre, p - base, 64);
      if ((unsigned)s >= (unsigned)Nn) s = 0;
      float4 x4 = *reinterpret_cast<const float4*>(C2 + (size_t)s * 32 + cg);
      float xl[4] = {x4.x, x4.y, x4.z, x4.w};
      float dot = 0.f;
#pragma unroll
      for (int k = 0; k < 4; k++) {
        float m = xl[k] + xr[k];
        float l = fmaxf(m, 0.2f * m);
        dot = fmaf(l, at[k], dot);
      }
      dot += dpp_mv<0xB1>(dot);  // xor1
      dot += dpp_mv<0x4E>(dot);  // xor2 -> edge score in all 4 lanes of slot
      dot = fminf(fmaxf(dot, -60.f), 60.f);
      float wgt = valid ? __expf(dot) : 0.f;
      denom += wgt;
#pragma unroll
      for (int k = 0; k < 4; k++) acc[k] = fmaf(wgt, xl[k], acc[k]);
    }
  }
  // merge 4 slots within each 16-lane row (rotations preserve lane&3 channel map)
  denom += dpp_mv<0x124>(denom);
  denom += dpp_mv<0x128>(denom);
#pragma unroll
  for (int k = 0; k < 4; k++) {
    acc[k] += dpp_mv<0x124>(acc[k]);
    acc[k] += dpp_mv<0x128>(acc[k]);
  }
  // merge the 4 rows
#pragma unroll
  for (int off = 16; off <= 32; off <<= 1) {
    denom += __shfl_xor(denom, off, 64);
#pragma unroll
    for (int k = 0; k < 4; k++) acc[k] += __shfl_xor(acc[k], off, 64);
  }

  float inv = __builtin_amdgcn_rcpf(denom + 1e-16f);
  ushort4 b4 = *reinterpret_cast<const ushort4*>(bias2 + cg);
  float bb[4] = {b2f(b4.x), b2f(b4.y), b2f(b4.z), b2f(b4.w)};
  float o[4];
#pragma unroll
  for (int k = 0; k < 4; k++) {
    o[k] = acc[k] * inv + bb[k];
    if (!(o[k] == o[k])) o[k] = 0.f;
  }
  // log_softmax over 16 channels (4 per lane across the 4 channel-lanes of a quad)
  float mx = fmaxf(fmaxf(o[0], o[1]), fmaxf(o[2], o[3]));
  mx = fmaxf(mx, dpp_mv<0xB1>(mx));
  mx = fmaxf(mx, dpp_mv<0x4E>(mx));
  float se = 0.f;
#pragma unroll
  for (int k = 0; k < 4; k++) se += __expf(o[k] - mx);
  se += dpp_mv<0xB1>(se);
  se += dpp_mv<0x4E>(se);
  float ls = logf(se);
  if (lane < 4) {
    float4 vo = {o[0], o[1], o[2], o[3]};
    float4 vl = {o[0] - mx - ls, o[1] - mx - ls, o[2] - mx - ls, o[3] - mx - ls};
    *reinterpret_cast<float4*>(out + (size_t)wid * 16 + cg) = vo;
    *reinterpret_cast<float4*>(out + (size_t)Nn * 16 + (size_t)wid * 16 + cg) = vl;
  }
}

extern "C" void kernel_launch(void* const* d_in, const int* in_sizes, int n_in,
                              void* d_out, int out_size, void* d_ws, size_t ws_size,
                              hipStream_t stream) {
  const void* x_raw = d_in[0];
  const int* ei     = (const int*)d_in[1];

  const int M = in_sizes[0] / 256;  // nodes (50000)
  const int E = in_sizes[1] / 2;    // raw edges (400000)
  const int TOT = E + M;            // edges incl. self-loops
  const int NX = M * 256;

  char* ws = (char*)d_ws;
  size_t off = 0;
  auto alloc = [&](size_t bytes) -> void* {
    void* p = ws + off;
    off = (off + bytes + 255) & ~(size_t)255;
    return p;
  };
  int*            flag   = (int*)alloc(4);
  unsigned short* Pc     = (unsigned short*)alloc((size_t)P_TOT * 2);
  unsigned short* Xc     = (unsigned short*)alloc((size_t)NX * 2);
  unsigned short* WT1    = (unsigned short*)alloc((size_t)512 * 256 * 2);
  unsigned short* WT2    = (unsigned short*)alloc((size_t)32 * 256 * 2);
  int*            cnt    = (int*)alloc((size_t)M * 4);
  int*            cursor = (int*)alloc((size_t)M * 4);
  int*            row_start = (int*)alloc((size_t)(M + 1) * 4);
  int*            csr_src   = (int*)alloc((size_t)TOT * 4);
  int*            blkTot = (int*)alloc(64 * 4);
  int*            blkOff = (int*)alloc(65 * 4);
  float*          C2     = (float*)alloc((size_t)M * 32 * 4);
  unsigned short* C1     = (unsigned short*)alloc((size_t)M * 512 * 2);
  const size_t need = off;
  (void)n_in;
  // H1 aliases Xc: gemm1 is the last reader of Xc (or reads x_raw directly);
  // agg1 writes H1 later.
  unsigned short* H1 = Xc;

  if (ws_size < need) {
    hipMemsetAsync(d_out, 0, (size_t)out_size * 4, stream);
    return;
  }

  unsigned short* bl1c   = Pc + 65536;
  unsigned short* br1c   = Pc + 131328;
  unsigned short* att1c  = Pc + 131584;
  unsigned short* bias1c = Pc + 131840;
  unsigned short* bl2c   = Pc + 136192;
  unsigned short* br2c   = Pc + 140304;
  unsigned short* att2c  = Pc + 140320;
  unsigned short* bias2c = Pc + 140336;

  hipMemsetAsync(cnt, 0, (size_t)M * 4, stream);

  // fused: conv_x | count | conv_params (each block self-probes dtype; block 0
  // publishes flag for gemm1)
  const int nb_convx = (NX / 4 + 255) / 256;
  const int nb_count = (TOT + 255) / 256;
  const int nb_convp = (P_TOT + 255) / 256;
  fused_pre_kernel<<<nb_convx + nb_count + nb_convp, 256, 0, stream>>>(
      x_raw, Xc, flag, NX, ei, E, M, cnt,
      d_in[2], d_in[3], d_in[4], d_in[5], d_in[6], d_in[7], d_in[8], d_in[9],
      d_in[10], d_in[11], d_in[12], d_in[13], Pc, nb_convx, nb_count);

  // fused: scan1 (+cursor zero) | transpose
  const int nb_scan = (M + 1023) / 1024;
  const int nb_tr = (512 * 256 + 32 * 256 + 1023) / 1024;
  fused_mid_kernel<<<nb_scan + nb_tr, 1024, 0, stream>>>(cnt, row_start, blkTot,
                                                         cursor, M, nb_scan, Pc, WT1, WT2);

  // fill (absorbs scan2: in-wave prefix over blkTot; block 0 publishes blkOff)
  fill_kernel<<<(TOT + 255) / 256, 256, 0, stream>>>(ei, E, M, row_start, blkTot,
                                                     nb_scan, cursor, csr_src, blkOff);

  const int nb_gemm = 4 * ((M + 127) / 128);
  gemm1_kernel<<<nb_gemm, 256, 0, stream>>>(Xc, (const unsigned short*)x_raw, flag,
                                            WT1, bl1c, br1c, C1, M);

  agg1_kernel<<<(M + 3) / 4, 256, 0, stream>>>(C1, att1c, bias1c, row_start, blkOff,
                                               csr_src, H1, M, TOT);

  gemm2_kernel<<<(M + 63) / 64, 256, 0, stream>>>(H1, WT2, bl2c, br2c, C2, M);

  agg2_kernel<<<(M + 3) / 4, 256, 0, stream>>>(C2, att2c, bias2c, row_start, blkOff,
                                               csr_src, (float*)d_out, M, TOT);
}